// Round 21
// baseline (34.040 us; speedup 1.0000x reference)
//
#include <hip/hip_runtime.h>
#include <stdint.h>
#include <math.h>

typedef unsigned long long u64;

#define CH     4096    // rows per K1 chunk
#define FTH    256     // K1 threads
#define SLOT   1280    // key slots per chunk (expected <=768, +20 sigma)
#define NT     1024    // K2 threads
#define KOUT   512
#define DIRECT 1024    // L <= DIRECT: keep all rows (chunk 0 only)
#define NBK    1024    // merge buckets
#define MAXB   48      // per-bucket guard
#define FNB    4096    // fallback bins
#define FCAP   2048    // fallback candidates
#define NCHMAX 16

__device__ __forceinline__ uint32_t fmap(float f) {
    uint32_t u = __float_as_uint(f);
    return (u & 0x80000000u) ? ~u : (u | 0x80000000u);
}
__device__ __forceinline__ float funmap(uint32_t m) {
    uint32_t u = (m & 0x80000000u) ? (m & 0x7fffffffu) : ~m;
    return __uint_as_float(u);
}
__device__ __forceinline__ u64 pack(float x, float y) {
    return ((u64)fmap(x) << 32) | (u64)fmap(y);
}

__device__ __forceinline__ float norm_icdf(float p) {
    const float a1=-3.969683028665376e+01f,a2= 2.209460984245205e+02f,a3=-2.759285104469687e+02f,
                a4= 1.383577518672690e+02f,a5=-3.066479806614716e+01f,a6= 2.506628277459239e+00f;
    const float b1=-5.447609879822406e+01f,b2= 1.615858368580409e+02f,b3=-1.556989798598866e+02f,
                b4= 6.680131188771972e+01f,b5=-1.328068155288572e+01f;
    const float c1=-7.784894002430293e-03f,c2=-3.223964580411365e-01f,c3=-2.400758277161838e+00f,
                c4=-2.549732539343734e+00f,c5= 4.374664141464968e+00f,c6= 2.938163982698783e+00f;
    const float d1= 7.784695709041462e-03f,d2= 3.224671290700398e-01f,d3= 2.445134137142996e+00f,
                d4= 3.754408661907416e+00f;
    if (p < 0.02425f) {
        float q = sqrtf(-2.0f * logf(p));
        return (((((c1*q+c2)*q+c3)*q+c4)*q+c5)*q+c6) / ((((d1*q+d2)*q+d3)*q+d4)*q+1.0f);
    } else if (p <= 0.97575f) {
        float q = p - 0.5f, r = q*q;
        return (((((a1*r+a2)*r+a3)*r+a4)*r+a5)*r+a6)*q / (((((b1*r+b2)*r+b3)*r+b4)*r+b5)*r+1.0f);
    } else {
        float q = sqrtf(-2.0f * logf(1.0f - p));
        return -(((((c1*q+c2)*q+c3)*q+c4)*q+c5)*q+c6) / ((((d1*q+d2)*q+d3)*q+d4)*q+1.0f);
    }
}

// K1: chunked streaming filter; survivors -> private per-chunk global region.
__global__ __launch_bounds__(FTH) void filter_kernel(
    const float* __restrict__ corners, const int* __restrict__ lengths,
    u64* __restrict__ keys, uint32_t* __restrict__ counts, int M, int NCH)
{
    const int blk = blockIdx.x;
    const int b = blk / NCH;
    const int q = blk - b * NCH;
    const int tid = threadIdx.x;

    int L = lengths[b];
    if (L < 0) L = 0;
    if (L > M) L = M;
    const int start = q * CH;
    int validq = L - start;
    if (validq < 0) validq = 0;
    if (validq > CH) validq = CH;

    u64* myk = keys + (size_t)blk * SLOT;
    if (validq == 0) { if (tid == 0) counts[blk] = 0u; return; }

    const float2* cp = (const float2*)corners + (size_t)b * M + start;

    if (L <= DIRECT) {               // only chunk 0 reaches here
        for (int i = tid; i < validq; i += FTH)
            myk[i] = pack(cp[i].x, cp[i].y);
        if (tid == 0) counts[blk] = (uint32_t)validq;
        return;
    }

    __shared__ uint32_t shcnt;
    if (tid == 0) shcnt = 0u;
    __syncthreads();

    const float tau = norm_icdf(768.0f / (float)L) + 0.01f;
    const int lane = tid & 63;
    const float4* cp4 = (const float4*)cp;
    const int nv = validq >> 1;

    for (int i = tid; i < nv; i += FTH) {
        float4 v = cp4[i];
        bool k0 = (v.x <= tau), k1 = (v.z <= tau);
        u64 m0 = __ballot(k0), m1 = __ballot(k1);
        if (m0 | m1) {
            int c0 = __popcll(m0);
            uint32_t base = 0;
            if (lane == 0) base = atomicAdd(&shcnt, (uint32_t)(c0 + __popcll(m1)));
            base = __shfl(base, 0, 64);
            u64 lt = ((u64)1 << lane) - 1ull;
            if (k0) {
                uint32_t s = base + (uint32_t)__popcll(m0 & lt);
                if (s < SLOT) myk[s] = pack(v.x, v.y);
            }
            if (k1) {
                uint32_t s = base + (uint32_t)(c0 + __popcll(m1 & lt));
                if (s < SLOT) myk[s] = pack(v.z, v.w);
            }
        }
    }
    if ((validq & 1) && tid == 0) {
        float2 c = cp[validq - 1];
        if (c.x <= tau) {
            uint32_t s = atomicAdd(&shcnt, 1u);
            if (s < SLOT) myk[s] = pack(c.x, c.y);
        }
    }
    __syncthreads();
    if (tid == 0) counts[blk] = shcnt;   // raw; >SLOT flags fallback
}

// K2: per batch: gather candidates, counting-sort rank, write sorted + pad.
__global__ __launch_bounds__(NT) void merge_kernel(
    const float* __restrict__ corners, const int* __restrict__ lengths,
    const u64* __restrict__ keys, const uint32_t* __restrict__ counts,
    float* __restrict__ out, int M, int NCH)
{
    const int b = blockIdx.x;
    const int tid = threadIdx.x;
    int L = lengths[b];
    if (L < 0) L = 0;
    if (L > M) L = M;
    const int Kb = (L < KOUT) ? L : KOUT;
    float2* outb = (float2*)(out + (size_t)b * (2 * KOUT));

    if (Kb == 0) {
        if (tid < KOUT) outb[tid] = make_float2(0.0f, 0.0f);
        return;
    }

    __shared__ u64 sbuf[NT];
    __shared__ uint32_t bh[NBK], sc[NBK];
    __shared__ uint32_t wsum[16];
    __shared__ uint32_t cnt8[NCHMAX];
    __shared__ uint32_t hist[FNB];   // fallback only
    __shared__ u64 fcand[FCAP];      // fallback only
    __shared__ uint32_t shcnt, shT, ovf, gbad, gn;

    if (tid < NCH) {
        uint32_t c = counts[b * NCH + tid];
        cnt8[tid] = (c > SLOT) ? SLOT : c;
        if (c > SLOT) gbad = 1u;     // benign race with init below? no: init first
    }
    if (tid == 0) { }                // (gbad/gn init done by thread 0 below)
    __syncthreads();
    if (tid == 0) {
        uint32_t bad = 0, run = 0;
        for (int q2 = 0; q2 < NCH; ++q2) {
            uint32_t c = counts[b * NCH + q2];
            if (c > SLOT) bad = 1u;
            run += (c > SLOT) ? SLOT : c;
        }
        gbad = bad; gn = run;
    }
    __syncthreads();
    const uint32_t n = gn;
    bool fb = (gbad != 0u) || (n < (uint32_t)Kb) || (n > (uint32_t)NT);

    if (!fb) {
        // ---- gather candidate tid from its chunk region ----
        u64 key = ~0ull;
        const bool valid = (tid < (int)n);
        if (valid) {
            uint32_t idx = (uint32_t)tid;
            int r = 0;
            while (idx >= cnt8[r]) { idx -= cnt8[r]; ++r; }
            key = keys[(size_t)(b * NCH + r) * SLOT + idx];
        }

        // ---- bucketed counting-sort rank (r14's proven merge) ----
        uint32_t bkt = 0;
        if (valid) {
            float x = funmap((uint32_t)(key >> 32));
            float p = 0.5f * (1.0f + erff(x * 0.70710678f));   // Phi(x)
            float s = (L > DIRECT) ? ((float)L * ((float)NBK / 768.0f))
                                   : (float)NBK;
            float fp = p * s;
            uint32_t bb = (uint32_t)fp;
            bkt = (bb > (NBK - 1u)) ? (NBK - 1u) : bb;
        }

        bh[tid] = 0u;
        if (tid == 0) ovf = 0u;
        __syncthreads();
        if (valid) atomicAdd(&bh[bkt], 1u);
        __syncthreads();

        {   // exclusive scan of bh -> sc
            const uint32_t c = bh[tid];
            const int lane = tid & 63, wid = tid >> 6;
            uint32_t v = c;
            for (int off = 1; off < 64; off <<= 1) {
                uint32_t t2 = __shfl_up(v, (unsigned)off, 64);
                if (lane >= off) v += t2;
            }
            if (lane == 63) wsum[wid] = v;
            __syncthreads();
            if (tid < 16) {
                uint32_t xv = wsum[tid];
                for (int off = 1; off < 16; off <<= 1) {
                    uint32_t t2 = __shfl_up(xv, (unsigned)off, 16);
                    if (tid >= off) xv += t2;
                }
                wsum[tid] = xv;
            }
            __syncthreads();
            const uint32_t woff = (wid > 0) ? wsum[wid - 1] : 0u;
            sc[tid] = v + woff - c;
        }
        __syncthreads();
        bh[tid] = 0u;
        __syncthreads();

        uint32_t pos = 0;
        if (valid) {
            uint32_t off = atomicAdd(&bh[bkt], 1u);
            pos = sc[bkt] + off;
            sbuf[pos] = key;
        }
        __syncthreads();
        if (valid && bh[bkt] > MAXB) ovf = 1u;
        __syncthreads();

        if (ovf == 0u) {
            uint32_t rank = 0;
            if (valid) {
                const uint32_t s0 = sc[bkt];
                const uint32_t cnt = bh[bkt];
                uint32_t r = 0;
                for (uint32_t m = 0; m < cnt; ++m) {
                    u64 kj = sbuf[s0 + m];
                    r += (kj < key) || (kj == key && (s0 + m) < pos);
                }
                rank = s0 + r;
            }
            if (tid >= Kb && tid < KOUT)
                outb[tid] = make_float2(0.0f, 0.0f);
            if (valid && rank < (uint32_t)Kb) {
                float2 o;
                o.x = funmap((uint32_t)(key >> 32));
                o.y = funmap((uint32_t)key);
                outb[rank] = o;
            }
            return;
        }
        fb = true;
    }

    // ---- exact fallback (statistically unreachable; guards exact) ----
    const float2* cp = (const float2*)corners + (size_t)b * M;
    __syncthreads();
    if (tid == 0) { shcnt = 0u; shT = FNB - 1; }
    for (int i = tid; i < FNB; i += NT) hist[i] = 0u;
    __syncthreads();
    for (int i = tid; i < L; i += NT)
        atomicAdd(&hist[fmap(cp[i].x) >> 20], 1u);
    __syncthreads();
    if (tid == 0) {
        uint32_t run = 0;
        for (int g = 0; g < FNB; ++g) {
            run += hist[g];
            if (run >= (uint32_t)Kb) { shT = (uint32_t)g; break; }
        }
    }
    __syncthreads();
    const uint32_t T = shT;
    for (int i = tid; i < L; i += NT) {
        float2 c = cp[i];
        uint32_t kx = fmap(c.x);
        if ((kx >> 20) <= T) {
            uint32_t p = atomicAdd(&shcnt, 1u);
            if (p < FCAP) fcand[p] = ((u64)kx << 32) | fmap(c.y);
        }
    }
    __syncthreads();
    const int nn = (int)((shcnt < FCAP) ? shcnt : FCAP);
    for (int jj = Kb + tid; jj < KOUT; jj += NT)
        outb[jj] = make_float2(0.0f, 0.0f);
    for (int i = tid; i < nn; i += NT) {
        u64 ki = fcand[i];
        uint32_t r = 0;
        for (int jj = 0; jj < nn; ++jj) {
            u64 kj = fcand[jj];
            r += (kj < ki) || (kj == ki && jj < i);
        }
        if (r < (uint32_t)Kb)
            outb[r] = make_float2(funmap((uint32_t)(ki >> 32)), funmap((uint32_t)ki));
    }
}

extern "C" void kernel_launch(void* const* d_in, const int* in_sizes, int n_in,
                              void* d_out, int out_size, void* d_ws, size_t ws_size,
                              hipStream_t stream) {
    const float* corners = (const float*)d_in[0];
    const int* lengths   = (const int*)d_in[1];
    float* out = (float*)d_out;
    const int B = in_sizes[1];
    const int M = in_sizes[0] / (B * 2);
    const int NCH = (M + CH - 1) / CH;   // 8 for M=32768

    u64* keys = (u64*)d_ws;
    uint32_t* counts = (uint32_t*)((char*)d_ws + (size_t)B * NCH * SLOT * sizeof(u64));

    filter_kernel<<<B * NCH, FTH, 0, stream>>>(corners, lengths, keys, counts, M, NCH);
    merge_kernel<<<B, NT, 0, stream>>>(corners, lengths, keys, counts, out, M, NCH);
}

// Round 22
// 22.663 us; speedup vs baseline: 1.5020x; 1.5020x over previous
//
#include <hip/hip_runtime.h>
#include <stdint.h>
#include <math.h>

typedef unsigned long long u64;

#define NT     1024
#define KOUT   512
#define DIRECT 1024     // L <= DIRECT: load rows directly, no filter
#define NBK    1024     // sort buckets
#define MAXB   48       // per-bucket guard
#define FNB    4096     // fallback histogram bins
#define FCAP   2048     // fallback candidate buffer

// Monotone float->uint32 map (order-preserving), exactly invertible.
__device__ __forceinline__ uint32_t fmap(float f) {
    uint32_t u = __float_as_uint(f);
    return (u & 0x80000000u) ? ~u : (u | 0x80000000u);
}
__device__ __forceinline__ float funmap(uint32_t m) {
    uint32_t u = (m & 0x80000000u) ? (m & 0x7fffffffu) : ~m;
    return __uint_as_float(u);
}
__device__ __forceinline__ u64 pack(float x, float y) {
    return ((u64)fmap(x) << 32) | (u64)fmap(y);
}

// Acklam inverse normal CDF (float); ~1e-3 accuracy, exactness guarded downstream.
__device__ __forceinline__ float norm_icdf(float p) {
    const float a1=-3.969683028665376e+01f,a2= 2.209460984245205e+02f,a3=-2.759285104469687e+02f,
                a4= 1.383577518672690e+02f,a5=-3.066479806614716e+01f,a6= 2.506628277459239e+00f;
    const float b1=-5.447609879822406e+01f,b2= 1.615858368580409e+02f,b3=-1.556989798598866e+02f,
                b4= 6.680131188771972e+01f,b5=-1.328068155288572e+01f;
    const float c1=-7.784894002430293e-03f,c2=-3.223964580411365e-01f,c3=-2.400758277161838e+00f,
                c4=-2.549732539343734e+00f,c5= 4.374664141464968e+00f,c6= 2.938163982698783e+00f;
    const float d1= 7.784695709041462e-03f,d2= 3.224671290700398e-01f,d3= 2.445134137142996e+00f,
                d4= 3.754408661907416e+00f;
    if (p < 0.02425f) {
        float q = sqrtf(-2.0f * logf(p));
        return (((((c1*q+c2)*q+c3)*q+c4)*q+c5)*q+c6) / ((((d1*q+d2)*q+d3)*q+d4)*q+1.0f);
    } else if (p <= 0.97575f) {
        float q = p - 0.5f, r = q*q;
        return (((((a1*r+a2)*r+a3)*r+a4)*r+a5)*r+a6)*q / (((((b1*r+b2)*r+b3)*r+b4)*r+b5)*r+1.0f);
    } else {
        float q = sqrtf(-2.0f * logf(1.0f - p));
        return -(((((c1*q+c2)*q+c3)*q+c4)*q+c5)*q+c6) / ((((d1*q+d2)*q+d3)*q+d4)*q+1.0f);
    }
}

__global__ __launch_bounds__(NT) void topk_kernel(
    const float* __restrict__ corners, const int* __restrict__ lengths,
    float* __restrict__ out, int M)
{
    const int b = blockIdx.x;
    const int tid = threadIdx.x;
    int L = lengths[b];
    if (L < 0) L = 0;
    if (L > M) L = M;
    const int Kb = (L < KOUT) ? L : KOUT;
    float2* outb = (float2*)(out + (size_t)b * (2 * KOUT));

    if (L == 0) {
        if (tid < KOUT) outb[tid] = make_float2(0.0f, 0.0f);
        return;
    }

    __shared__ u64 sbuf[NT];         // candidate buffer / scatter target
    __shared__ uint32_t bh[NBK];     // bucket counts
    __shared__ uint32_t sc[NBK];     // bucket starts (exclusive scan)
    __shared__ uint32_t wsum[16];
    __shared__ uint32_t hist[FNB];   // fallback only
    __shared__ u64 fcand[FCAP];      // fallback only
    __shared__ uint32_t shcnt, shT, ovf;

    const float2* cp = (const float2*)corners + (size_t)b * M;
    bool fb = false;
    uint32_t n = 0;

    if (L <= DIRECT) {
        // ---- direct path: every valid row is a candidate ----
        n = (uint32_t)L;
        sbuf[tid] = (tid < L) ? pack(cp[tid].x, cp[tid].y) : ~0ull;
    } else {
        // ---- filtered path: keep x <= tau(L), expected n ~ 768 +- 28.
        //      Per-lane direct append: survivors are ~2.3% of rows, so the
        //      LDS atomic runs on few lanes; no per-iteration ballot/shfl. ----
        if (tid == 0) shcnt = 0u;
        __syncthreads();
        const float tau = norm_icdf(768.0f / (float)L) + 0.01f;
        const float4* cp4 = (const float4*)cp;
        const int nv = L >> 1;

        for (int i = tid; i < nv; i += NT) {
            float4 v = cp4[i];
            if (v.x <= tau) {
                uint32_t s = atomicAdd(&shcnt, 1u);
                if (s < NT) sbuf[s] = pack(v.x, v.y);
            }
            if (v.z <= tau) {
                uint32_t s = atomicAdd(&shcnt, 1u);
                if (s < NT) sbuf[s] = pack(v.z, v.w);
            }
        }
        if ((L & 1) && tid == 0) {
            float2 c = cp[L - 1];
            if (c.x <= tau) {
                uint32_t s = atomicAdd(&shcnt, 1u);
                if (s < NT) sbuf[s] = pack(c.x, c.y);
            }
        }
        __syncthreads();
        n = shcnt;
        if (n < (uint32_t)Kb || n > NT) fb = true;     // block-uniform
        else if (tid >= (int)n) sbuf[tid] = ~0ull;     // sentinel-pad
    }

    if (!fb) {
        __syncthreads();   // sbuf fully populated

        // ---- bucketed counting-sort rank ----
        u64 key = sbuf[tid];
        const bool valid = (tid < (int)n);
        uint32_t bkt = 0;
        if (valid) {
            float x = funmap((uint32_t)(key >> 32));
            float p = 0.5f * (1.0f + erff(x * 0.70710678f));   // Phi(x)
            float s = (L > DIRECT) ? ((float)L * ((float)NBK / 768.0f))
                                   : (float)NBK;
            float fp = p * s;
            uint32_t bb = (uint32_t)fp;
            bkt = (bb > (NBK - 1u)) ? (NBK - 1u) : bb;
        }

        bh[tid] = 0u;
        if (tid == 0) ovf = 0u;
        __syncthreads();
        if (valid) atomicAdd(&bh[bkt], 1u);
        __syncthreads();

        // exclusive scan of bh -> sc (wave shuffle scan + wave-sum scan)
        {
            const uint32_t c = bh[tid];
            const int lane = tid & 63, wid = tid >> 6;
            uint32_t v = c;
            for (int off = 1; off < 64; off <<= 1) {
                uint32_t t2 = __shfl_up(v, (unsigned)off, 64);
                if (lane >= off) v += t2;
            }
            if (lane == 63) wsum[wid] = v;
            __syncthreads();
            if (tid < 16) {
                uint32_t xv = wsum[tid];
                for (int off = 1; off < 16; off <<= 1) {
                    uint32_t t2 = __shfl_up(xv, (unsigned)off, 16);
                    if (tid >= off) xv += t2;
                }
                wsum[tid] = xv;
            }
            __syncthreads();
            const uint32_t woff = (wid > 0) ? wsum[wid - 1] : 0u;
            sc[tid] = v + woff - c;
        }
        __syncthreads();
        bh[tid] = 0u;
        __syncthreads();

        // scatter by bucket (keys already in registers; sbuf reusable)
        uint32_t pos = 0;
        if (valid) {
            uint32_t off = atomicAdd(&bh[bkt], 1u);
            pos = sc[bkt] + off;
            sbuf[pos] = key;
        }
        __syncthreads();
        if (valid && bh[bkt] > MAXB) ovf = 1u;   // benign race, all write 1
        __syncthreads();

        if (ovf == 0u) {   // block-uniform
            // exact global rank = bucket start + rank within bucket
            uint32_t rank = 0;
            if (valid) {
                const uint32_t s0 = sc[bkt];
                const uint32_t cnt = bh[bkt];
                uint32_t r = 0;
                for (uint32_t m = 0; m < cnt; ++m) {
                    u64 kj = sbuf[s0 + m];
                    r += (kj < key) || (kj == key && (s0 + m) < pos);
                }
                rank = s0 + r;
            }
            if (tid >= Kb && tid < KOUT)
                outb[tid] = make_float2(0.0f, 0.0f);
            if (valid && rank < (uint32_t)Kb) {
                float2 o;
                o.x = funmap((uint32_t)(key >> 32));
                o.y = funmap((uint32_t)key);
                outb[rank] = o;
            }
            return;
        }
        // bucket overflow (statistically unreachable) -> exact fallback below
    }

    // ---- exact fallback (statistically unreachable; guards exact) ----
    __syncthreads();
    if (tid == 0) { shcnt = 0u; shT = FNB - 1; }
    for (int i = tid; i < FNB; i += NT) hist[i] = 0u;
    __syncthreads();
    for (int i = tid; i < L; i += NT)
        atomicAdd(&hist[fmap(cp[i].x) >> 20], 1u);
    __syncthreads();
    if (tid == 0) {
        uint32_t run = 0;
        for (int g = 0; g < FNB; ++g) {
            run += hist[g];
            if (run >= (uint32_t)Kb) { shT = (uint32_t)g; break; }
        }
    }
    __syncthreads();
    const uint32_t T = shT;
    for (int i = tid; i < L; i += NT) {
        float2 c = cp[i];
        uint32_t kx = fmap(c.x);
        if ((kx >> 20) <= T) {
            uint32_t p = atomicAdd(&shcnt, 1u);
            if (p < FCAP) fcand[p] = ((u64)kx << 32) | fmap(c.y);
        }
    }
    __syncthreads();
    const int nn = (int)((shcnt < FCAP) ? shcnt : FCAP);
    for (int jj = Kb + tid; jj < KOUT; jj += NT)
        outb[jj] = make_float2(0.0f, 0.0f);
    for (int i = tid; i < nn; i += NT) {
        u64 ki = fcand[i];
        uint32_t r = 0;
        for (int jj = 0; jj < nn; ++jj) {
            u64 kj = fcand[jj];
            r += (kj < ki) || (kj == ki && jj < i);
        }
        if (r < (uint32_t)Kb)
            outb[r] = make_float2(funmap((uint32_t)(ki >> 32)), funmap((uint32_t)ki));
    }
}

extern "C" void kernel_launch(void* const* d_in, const int* in_sizes, int n_in,
                              void* d_out, int out_size, void* d_ws, size_t ws_size,
                              hipStream_t stream) {
    const float* corners = (const float*)d_in[0];
    const int* lengths   = (const int*)d_in[1];
    float* out = (float*)d_out;
    const int B = in_sizes[1];
    const int M = in_sizes[0] / (B * 2);
    topk_kernel<<<B, NT, 0, stream>>>(corners, lengths, out, M);
}